// Round 16
// baseline (509.949 us; speedup 1.0000x reference)
//
#include <hip/hip_runtime.h>
#include <cstdint>

typedef unsigned short u16;
typedef u16   u16x4 __attribute__((ext_vector_type(4)));
typedef u16   u16x8 __attribute__((ext_vector_type(8)));
typedef short s16x8 __attribute__((ext_vector_type(8)));
typedef float f32x4 __attribute__((ext_vector_type(4)));
typedef float f32x16 __attribute__((ext_vector_type(16)));

__device__ __forceinline__ u16 f2bf(float f) {
  union { float f; unsigned u; } v; v.f = f;
  unsigned u = v.u;
  return (u16)((u + 0x7fffu + ((u >> 16) & 1u)) >> 16);
}

__device__ __forceinline__ void gld_lds16(const u16* g, u16* l) {
  __builtin_amdgcn_global_load_lds((const __attribute__((address_space(1))) void*)g,
                                   (__attribute__((address_space(3))) void*)l, 16, 0, 0);
}

// ---------------- fused prep: cast x + transpose-cast both weight matrices ----------
__device__ __forceinline__ void transpose_cast_body(
    const float* __restrict__ in, u16* __restrict__ outp, int R, int Cin,
    int cx, int cy, u16 (*tile)[72]) {
  const int c0 = cx * 64, r0 = cy * 64;
  const int t = threadIdx.x;
  const int r = t >> 2, cs = (t & 3) * 16;
  const float* src = in + (size_t)(r0 + r) * Cin + c0 + cs;
#pragma unroll
  for (int q = 0; q < 4; ++q) {
    float4 v = *(const float4*)(src + q * 4);
    tile[r][cs + q * 4 + 0] = f2bf(v.x);
    tile[r][cs + q * 4 + 1] = f2bf(v.y);
    tile[r][cs + q * 4 + 2] = f2bf(v.z);
    tile[r][cs + q * 4 + 3] = f2bf(v.w);
  }
  __syncthreads();
  u16x8 w0, w1;
#pragma unroll
  for (int q = 0; q < 8; ++q) { w0[q] = tile[cs + q][r]; w1[q] = tile[cs + 8 + q][r]; }
  u16* dst = outp + (size_t)(c0 + r) * R + r0 + cs;
  *(u16x8*)dst = w0;
  *(u16x8*)(dst + 8) = w1;
}

__global__ void prep_k(const float* __restrict__ x, u16* __restrict__ xb,
                       const float* __restrict__ w_attn, u16* __restrict__ waT,
                       const float* __restrict__ w_proj, u16* __restrict__ wpT) {
  __shared__ u16 tile[64][72];
  const int bx = blockIdx.x;
  if (bx < 8192) {
    size_t i = ((size_t)bx * 256 + threadIdx.x) * 8;
    float4 a = *(const float4*)(x + i);
    float4 b = *(const float4*)(x + i + 4);
    u16x8 r;
    r[0] = f2bf(a.x); r[1] = f2bf(a.y); r[2] = f2bf(a.z); r[3] = f2bf(a.w);
    r[4] = f2bf(b.x); r[5] = f2bf(b.y); r[6] = f2bf(b.z); r[7] = f2bf(b.w);
    *(u16x8*)(xb + i) = r;
  } else if (bx < 11264) {
    int idx = bx - 8192;
    transpose_cast_body(w_attn, waT, 2048, 6144, idx % 96, idx / 96, tile);
  } else {
    int idx = bx - 11264;
    transpose_cast_body(w_proj, wpT, 2048, 2048, idx % 32, idx / 32, tile);
  }
}

// ---------------- GEMM 256x256, BK=64, 8 waves, 4-phase (R13 skeleton) ----
// MFMA shape switched 16x16x32 -> 32x32x16 (m119: +15% rate, half the instr count).
// Per wave: 4x2 tiles of 32x32. Phases (same units/waits as R13):
//   ph0: m{0,1}(unit A0) x n0(unit B0) | ph1: m{0,1} x n1(B1)
//   ph2: m{2,3}(A1) x n1               | ph3: m{2,3} x n0 (bf0 live)
// A-frag: row=lane&31, k=(lane>>5)*8+i (16x16 analog). C/D per m74/m101:
//   col=lane&31, row=(reg&3)+8*(reg>>2)+4*(lane>>5).
// LDS layout/staging byte-identical to R13 (coalesced + XOR source-swizzle).
template <int EPI>
__global__ __launch_bounds__(512, 2) void gemm256(
    const u16* __restrict__ A, const u16* __restrict__ Bt,
    const float* __restrict__ bias,
    u16* __restrict__ o0, u16* __restrict__ o1, u16* __restrict__ o2,
    float* __restrict__ ofp, int Ntiles, int Kdim) {
  __shared__ __align__(128) u16 sm[65536];  // 128 KB
  const int nwg = gridDim.x;
  const int orig = blockIdx.x;
  const int qq = nwg >> 3;                        // grids are multiples of 8
  const int bid = (orig & 7) * qq + (orig >> 3);  // bijective XCD swizzle
  const int mt = bid / Ntiles, nt = bid % Ntiles;
  const int tid = threadIdx.x, lane = tid & 63, wave = tid >> 6;
  const int wr = wave >> 2, wc = wave & 3;        // 2M x 4N waves, 128x64 out each
  const int l31 = lane & 31, lk = lane >> 5;
  const int q7 = l31 & 7, q3 = l31 >> 3;
  f32x16 acc[4][2] = {};
  const int nK = Kdim >> 6;

#define VMA(n) asm volatile("s_waitcnt vmcnt(" #n ")" ::: "memory")
#define BARK   asm volatile("s_barrier" ::: "memory")
  // A-frags for m-tiles {mb, mb+1}: unit = mb>>1; rowL = wr*64+(mi&1)*32+l31
#define DSA(mb)                                                                          \
  do {                                                                                   \
    _Pragma("unroll") for (int m2 = 0; m2 < 2; ++m2)                                     \
    _Pragma("unroll") for (int kk = 0; kk < 4; ++kk)                                     \
      af[m2 * 4 + kk] = *(const s16x8*)&sm[(size_t)(cA + ((mb) >> 1) * 1024 +            \
          (wr * 8 + m2 * 4 + q3) * 64 + q7 * 8 + (((kk) * 2 + lk) ^ q7)) * 8];           \
  } while (0)
  // B-frags for n-tile nj: unit = nj; colL = wc*32 + l31
#define DSB(dst, nj)                                                                     \
  do {                                                                                   \
    _Pragma("unroll") for (int kk = 0; kk < 4; ++kk)                                     \
      dst[kk] = *(const s16x8*)&sm[(size_t)(cB + (nj) * 1024 +                           \
          (wc * 4 + q3) * 64 + q7 * 8 + (((kk) * 2 + lk) ^ q7)) * 8];                    \
  } while (0)
#define STA(unit, k0, sbase)                                                             \
  do {                                                                                   \
    _Pragma("unroll") for (int l = 0; l < 2; ++l) {                                      \
      int c = l * 512 + tid;                                                             \
      int mid = (c >> 3) & 7;                                                            \
      int rowL = (c >> 6) * 8 + mid, khi = (c & 7) ^ mid;                                \
      int prow = (rowL >> 6) * 128 + (unit) * 64 + (rowL & 63);                          \
      gld_lds16(A + (size_t)(mt * 256 + prow) * Kdim + (k0) + khi * 8,                   \
                &sm[(size_t)((sbase) + (unit)*1024 + l * 512 + wave * 64) * 8]);         \
    }                                                                                    \
  } while (0)
#define STB(unit, k0, sbase)                                                             \
  do {                                                                                   \
    _Pragma("unroll") for (int l = 0; l < 2; ++l) {                                      \
      int c = l * 512 + tid;                                                             \
      int mid = (c >> 3) & 7;                                                            \
      int colL = (c >> 6) * 8 + mid, khi = (c & 7) ^ mid;                                \
      int pcol = (colL >> 5) * 64 + (unit) * 32 + (colL & 31);                           \
      gld_lds16(Bt + (size_t)(nt * 256 + pcol) * Kdim + (k0) + khi * 8,                  \
                &sm[(size_t)((sbase) + (unit)*1024 + l * 512 + wave * 64) * 8]);         \
    }                                                                                    \
  } while (0)
#define MM(mb, nj, BF)                                                                   \
  do {                                                                                   \
    __builtin_amdgcn_s_setprio(1);                                                       \
    _Pragma("unroll") for (int m2 = 0; m2 < 2; ++m2)                                     \
    _Pragma("unroll") for (int kk = 0; kk < 4; ++kk)                                     \
      acc[(mb) + m2][nj] = __builtin_amdgcn_mfma_f32_32x32x16_bf16(                      \
          af[m2 * 4 + kk], BF[kk], acc[(mb) + m2][nj], 0, 0, 0);                         \
    __builtin_amdgcn_s_setprio(0);                                                       \
  } while (0)

  STA(0, 0, 0); STB(0, 0, 4096); STB(1, 0, 4096); STA(1, 0, 0);
  VMA(4);
  BARK;

  for (int t = 0; t < nK; ++t) {
    const int cA = (t & 1) * 2048, cB = 4096 + (t & 1) * 2048;
    const int sA = ((t & 1) ^ 1) * 2048, sB = 4096 + ((t & 1) ^ 1) * 2048;
    const int k1 = (t + 1) << 6;
    const bool st = (t + 1 < nK);
    s16x8 af[8], bf0[4], bf1[4];
    // ph0: m{0,1} x n0
    DSA(0); DSB(bf0, 0);
    if (st) { STA(0, k1, sA); VMA(4); } else { VMA(2); }
    BARK; MM(0, 0, bf0); BARK;
    // ph1: m{0,1} x n1
    DSB(bf1, 1);
    if (st) { STB(0, k1, sB); VMA(4); } else { VMA(0); }
    BARK; MM(0, 1, bf1); BARK;
    // ph2: m{2,3} x n1
    DSA(2);
    if (st) STB(1, k1, sB);
    BARK; MM(2, 1, bf1); BARK;
    // ph3: m{2,3} x n0 — bf0 kept live
    if (st) { STA(1, k1, sA); VMA(4); }
    BARK; MM(2, 0, bf0); BARK;
  }
#undef VMA
#undef BARK
#undef DSA
#undef DSB
#undef STA
#undef STB
#undef MM

  const int row0 = mt * 256 + wr * 128;
  const int col0 = nt * 256 + wc * 64;
  float bcol[2];
#pragma unroll
  for (int nj = 0; nj < 2; ++nj) bcol[nj] = bias[col0 + nj * 32 + l31];
  if constexpr (EPI == 0) {
#pragma unroll
    for (int nj = 0; nj < 2; ++nj) {
      int cc = col0 + nj * 32 + l31;
      int which = cc >> 11, h = (cc >> 7) & 15, d = cc & 127;
      if (which == 2) {
        // V: write transposed Vt[bh][d][t]; regs 4g..4g+3 = 4 consecutive rows
#pragma unroll
        for (int mi = 0; mi < 4; ++mi)
#pragma unroll
          for (int g = 0; g < 4; ++g) {
            int t0 = row0 + mi * 32 + g * 8 + lk * 4;
            int bb = t0 >> 11, tt = t0 & 2047;
            u16x4 w;
#pragma unroll
            for (int j = 0; j < 4; ++j) w[j] = f2bf(acc[mi][nj][g * 4 + j] + bcol[nj]);
            *(u16x4*)&o2[(((size_t)bb * 16 + h) * 128 + d) * 2048 + tt] = w;
          }
      } else {
        u16* o = (which == 0) ? o0 : o1;
#pragma unroll
        for (int mi = 0; mi < 4; ++mi)
#pragma unroll
          for (int g = 0; g < 4; ++g)
#pragma unroll
            for (int j = 0; j < 4; ++j) {
              int row = row0 + mi * 32 + g * 8 + lk * 4 + j;
              int bb = row >> 11, tt = row & 2047;
              o[(((size_t)bb * 16 + h) * 2048 + tt) * 128 + d] =
                  f2bf(acc[mi][nj][g * 4 + j] + bcol[nj]);
            }
      }
    }
  } else {
#pragma unroll
    for (int mi = 0; mi < 4; ++mi)
#pragma unroll
      for (int g = 0; g < 4; ++g)
#pragma unroll
        for (int j = 0; j < 4; ++j) {
          int row = row0 + mi * 32 + g * 8 + lk * 4 + j;
#pragma unroll
          for (int nj = 0; nj < 2; ++nj)
            ofp[(size_t)row * 2048 + col0 + nj * 32 + l31] =
                acc[mi][nj][g * 4 + j] + bcol[nj];
        }
  }
}

// ---------------- flash attention v5 (R15-exact, frozen) ----------------
__global__ __launch_bounds__(512, 4) void attn_k(
    const u16* __restrict__ Q, const u16* __restrict__ Kg,
    const u16* __restrict__ Vt, u16* __restrict__ Y) {
  __shared__ u16 Ks[8192];
  __shared__ u16 Vs[8192];
  __shared__ u16 Ps[8][16 * 72];
  const int bh = blockIdx.x, p = blockIdx.y;   // bh fastest -> XCD-local K/V
  const int tid = threadIdx.x, lane = tid & 63, wave = tid >> 6;
  const int l15 = lane & 15, lhi = lane >> 4;
  const size_t bhT = (size_t)bh * 2048;
  const int b = bh >> 4, h = bh & 15;
  const float sc = 0.08838834764831845f * 1.4426950408889634f;

  for (int hf = 0; hf < 2; ++hf) {
    const int qt = hf ? 15 - p : p;
    const int r0 = qt * 128 + wave * 16;
    const int last = 2 * qt + 1;

    s16x8 qf[4];
#pragma unroll
    for (int kk = 0; kk < 4; ++kk)
      qf[kk] = *(const s16x8*)&Q[(bhT + r0 + l15) * 128 + kk * 32 + lhi * 8];

    f32x4 o[8] = {};
    float m_[4], l_[4];
#pragma unroll
    for (int j = 0; j < 4; ++j) { m_[j] = -1e30f; l_[j] = 0.f; }

    __syncthreads();
#pragma unroll
    for (int c = 0; c < 2; ++c) {
      int ci = c * 512 + tid;
      int dhi = ci >> 6, key = ci & 63;
      gld_lds16(Kg + (bhT + key) * 128 + dhi * 8, &Ks[(c * 512 + wave * 64) * 8]);
      int khi = ci >> 7, d = ci & 127;
      gld_lds16(Vt + ((size_t)bh * 128 + d) * 2048 + khi * 8, &Vs[(c * 512 + wave * 64) * 8]);
    }
    __syncthreads();

    for (int it = 0; it <= last; ++it) {
      const int j0 = it * 64;
      const bool have_next = (it < last);
      u16x8 kpre[2], vpre[2];
      if (have_next) {
        const int j1 = j0 + 64;
#pragma unroll
        for (int c = 0; c < 2; ++c) {
          int ci = c * 512 + tid;
          int dhi = ci >> 6, key = ci & 63;
          kpre[c] = *(const u16x8*)&Kg[(bhT + j1 + key) * 128 + dhi * 8];
          int khi = ci >> 7, d = ci & 127;
          vpre[c] = *(const u16x8*)&Vt[((size_t)bh * 128 + d) * 2048 + j1 + khi * 8];
        }
      }

      if (j0 <= r0 + 15) {
        f32x4 s[4] = {};
        __builtin_amdgcn_s_setprio(1);
#pragma unroll
        for (int nc = 0; nc < 4; ++nc)
#pragma unroll
          for (int kk = 0; kk < 4; ++kk) {
            s16x8 kf = *(const s16x8*)&Ks[((kk * 4 + lhi) * 64 + nc * 16 + l15) * 8];
            s[nc] = __builtin_amdgcn_mfma_f32_16x16x32_bf16(qf[kk], kf, s[nc], 0, 0, 0);
          }
        __builtin_amdgcn_s_setprio(0);
        const bool maskt = (j0 + 63 > r0);
        float rmax[4];
#pragma unroll
        for (int j = 0; j < 4; ++j) rmax[j] = -1e30f;
#pragma unroll
        for (int nc = 0; nc < 4; ++nc)
#pragma unroll
          for (int j = 0; j < 4; ++j) {
            float v = s[nc][j] * sc;
            if (maskt && (j0 + nc * 16 + l15) > (r0 + lhi * 4 + j)) v = -1e30f;
            s[nc][j] = v;
            rmax[j] = fmaxf(rmax[j], v);
          }
#pragma unroll
        for (int off = 1; off < 16; off <<= 1)
#pragma unroll
          for (int j = 0; j < 4; ++j) rmax[j] = fmaxf(rmax[j], __shfl_xor(rmax[j], off));

        bool up = false;
#pragma unroll
        for (int j = 0; j < 4; ++j) up |= (rmax[j] > m_[j] + 8.f);
        if (__any(up)) {
#pragma unroll
          for (int j = 0; j < 4; ++j) {
            float mn = fmaxf(m_[j], rmax[j]);
            float al = exp2f(m_[j] - mn);
            m_[j] = mn;
            l_[j] *= al;
#pragma unroll
            for (int di = 0; di < 8; ++di) o[di][j] *= al;
          }
        }
        float rsum[4];
#pragma unroll
        for (int j = 0; j < 4; ++j) rsum[j] = 0.f;
#pragma unroll
        for (int nc = 0; nc < 4; ++nc)
#pragma unroll
          for (int j = 0; j < 4; ++j) {
            float pv = exp2f(s[nc][j] - m_[j]);
            rsum[j] += pv;
            Ps[wave][(lhi * 4 + j) * 72 + nc * 16 + l15] = f2bf(pv);
          }
#pragma unroll
        for (int off = 1; off < 16; off <<= 1)
#pragma unroll
          for (int j = 0; j < 4; ++j) rsum[j] += __shfl_xor(rsum[j], off);
#pragma unroll
        for (int j = 0; j < 4; ++j) l_[j] += rsum[j];

        __builtin_amdgcn_s_setprio(1);
#pragma unroll
        for (int kk2 = 0; kk2 < 2; ++kk2) {
          s16x8 pf = *(const s16x8*)&Ps[wave][l15 * 72 + kk2 * 32 + lhi * 8];
#pragma unroll
          for (int di = 0; di < 8; ++di) {
            s16x8 vf = *(const s16x8*)&Vs[((kk2 * 4 + lhi) * 128 + di * 16 + l15) * 8];
            o[di] = __builtin_amdgcn_mfma_f32_16x16x32_bf16(pf, vf, o[di], 0, 0, 0);
          }
        }
        __builtin_amdgcn_s_setprio(0);
      }

      if (have_next) {
        __syncthreads();
#pragma unroll
        for (int c = 0; c < 2; ++c) {
          *(u16x8*)&Ks[(c * 512 + tid) * 8] = kpre[c];
          *(u16x8*)&Vs[(c * 512 + tid) * 8] = vpre[c];
        }
        __syncthreads();
      }
    }

    float rl[4];
#pragma unroll
    for (int j = 0; j < 4; ++j) rl[j] = 1.0f / l_[j];
#pragma unroll
    for (int di = 0; di < 8; ++di)
#pragma unroll
      for (int j = 0; j < 4; ++j) {
        int row = b * 2048 + r0 + lhi * 4 + j;
        int col = h * 128 + di * 16 + l15;
        Y[(size_t)row * 2048 + col] = f2bf(o[di][j] * rl[j]);
      }
  }
}

extern "C" void kernel_launch(void* const* d_in, const int* in_sizes, int n_in,
                              void* d_out, int out_size, void* d_ws, size_t ws_size,
                              hipStream_t stream) {
  const float* x      = (const float*)d_in[0];
  const float* w_attn = (const float*)d_in[1];
  const float* b_attn = (const float*)d_in[2];
  const float* w_proj = (const float*)d_in[3];
  const float* b_proj = (const float*)d_in[4];
  float* out = (float*)d_out;

  char* ws = (char*)d_ws;
  u16* xb  = (u16*)(ws);                      // x bf16 [8192][2048]
  u16* waT = (u16*)(ws + 33554432ull);        // w_attn^T bf16 [6144][2048]
  u16* wpT = (u16*)(ws + 58720256ull);        // w_proj^T bf16 [2048][2048]
  u16* Qb  = (u16*)(ws + 67108864ull);        // [B,H,T,D]
  u16* Kb  = (u16*)(ws + 100663296ull);
  u16* Vtb = (u16*)(ws + 167772160ull);       // [B,H,D,T] (written by gemm1 epilogue)
  u16* Yb  = xb;                              // reuse (xb dead after gemm1)

  prep_k<<<12288, 256, 0, stream>>>(x, xb, w_attn, waT, w_proj, wpT);
  gemm256<0><<<32 * 24, 512, 0, stream>>>(xb, waT, b_attn, Qb, Kb, Vtb, nullptr, 24, 2048);
  attn_k<<<dim3(64, 8), 512, 0, stream>>>(Qb, Kb, Vtb, Yb);
  gemm256<1><<<32 * 8, 512, 0, stream>>>(Yb, wpT, b_proj, nullptr, nullptr, nullptr, out, 8, 2048);
}

// Round 17
// 480.210 us; speedup vs baseline: 1.0619x; 1.0619x over previous
//
#include <hip/hip_runtime.h>
#include <cstdint>

typedef unsigned short u16;
typedef u16   u16x4 __attribute__((ext_vector_type(4)));
typedef u16   u16x8 __attribute__((ext_vector_type(8)));
typedef short s16x8 __attribute__((ext_vector_type(8)));
typedef float f32x4 __attribute__((ext_vector_type(4)));

__device__ __forceinline__ u16 f2bf(float f) {
  union { float f; unsigned u; } v; v.f = f;
  unsigned u = v.u;
  return (u16)((u + 0x7fffu + ((u >> 16) & 1u)) >> 16);
}

__device__ __forceinline__ void gld_lds16(const u16* g, u16* l) {
  __builtin_amdgcn_global_load_lds((const __attribute__((address_space(1))) void*)g,
                                   (__attribute__((address_space(3))) void*)l, 16, 0, 0);
}

// ---------------- fused prep: cast x + transpose-cast both weight matrices ----------
__device__ __forceinline__ void transpose_cast_body(
    const float* __restrict__ in, u16* __restrict__ outp, int R, int Cin,
    int cx, int cy, u16 (*tile)[72]) {
  const int c0 = cx * 64, r0 = cy * 64;
  const int t = threadIdx.x;
  const int r = t >> 2, cs = (t & 3) * 16;
  const float* src = in + (size_t)(r0 + r) * Cin + c0 + cs;
#pragma unroll
  for (int q = 0; q < 4; ++q) {
    float4 v = *(const float4*)(src + q * 4);
    tile[r][cs + q * 4 + 0] = f2bf(v.x);
    tile[r][cs + q * 4 + 1] = f2bf(v.y);
    tile[r][cs + q * 4 + 2] = f2bf(v.z);
    tile[r][cs + q * 4 + 3] = f2bf(v.w);
  }
  __syncthreads();
  u16x8 w0, w1;
#pragma unroll
  for (int q = 0; q < 8; ++q) { w0[q] = tile[cs + q][r]; w1[q] = tile[cs + 8 + q][r]; }
  u16* dst = outp + (size_t)(c0 + r) * R + r0 + cs;
  *(u16x8*)dst = w0;
  *(u16x8*)(dst + 8) = w1;
}

__global__ void prep_k(const float* __restrict__ x, u16* __restrict__ xb,
                       const float* __restrict__ w_attn, u16* __restrict__ waT,
                       const float* __restrict__ w_proj, u16* __restrict__ wpT) {
  __shared__ u16 tile[64][72];
  const int bx = blockIdx.x;
  if (bx < 8192) {
    size_t i = ((size_t)bx * 256 + threadIdx.x) * 8;
    float4 a = *(const float4*)(x + i);
    float4 b = *(const float4*)(x + i + 4);
    u16x8 r;
    r[0] = f2bf(a.x); r[1] = f2bf(a.y); r[2] = f2bf(a.z); r[3] = f2bf(a.w);
    r[4] = f2bf(b.x); r[5] = f2bf(b.y); r[6] = f2bf(b.z); r[7] = f2bf(b.w);
    *(u16x8*)(xb + i) = r;
  } else if (bx < 11264) {
    int idx = bx - 8192;
    transpose_cast_body(w_attn, waT, 2048, 6144, idx % 96, idx / 96, tile);
  } else {
    int idx = bx - 11264;
    transpose_cast_body(w_proj, wpT, 2048, 2048, idx % 32, idx / 32, tile);
  }
}

// ---------------- GEMM 256x256, BK=64, 8 waves, 4-phase (R13-exact, frozen) ----
template <int EPI>
__global__ __launch_bounds__(512, 2) void gemm256(
    const u16* __restrict__ A, const u16* __restrict__ Bt,
    const float* __restrict__ bias,
    u16* __restrict__ o0, u16* __restrict__ o1, u16* __restrict__ o2,
    float* __restrict__ ofp, int Ntiles, int Kdim) {
  __shared__ __align__(128) u16 sm[65536];  // 128 KB
  const int nwg = gridDim.x;
  const int orig = blockIdx.x;
  const int qq = nwg >> 3;                        // grids are multiples of 8
  const int bid = (orig & 7) * qq + (orig >> 3);  // bijective XCD swizzle
  const int mt = bid / Ntiles, nt = bid % Ntiles;
  const int tid = threadIdx.x, lane = tid & 63, wave = tid >> 6;
  const int wr = wave >> 2, wc = wave & 3;        // 2M x 4N waves, 128x64 out each
  const int l15 = lane & 15, lhi = lane >> 4;
  const int r7 = l15 & 7, r3 = l15 >> 3;
  f32x4 acc[8][4] = {};
  const int nK = Kdim >> 6;

#define VMA(n) asm volatile("s_waitcnt vmcnt(" #n ")" ::: "memory")
#define BARK   asm volatile("s_barrier" ::: "memory")
#define DSA(qm)                                                                          \
  do {                                                                                   \
    _Pragma("unroll") for (int mi = 0; mi < 4; ++mi)                                     \
    _Pragma("unroll") for (int kk = 0; kk < 2; ++kk)                                     \
      af[mi * 2 + kk] = *(const s16x8*)&sm[(size_t)(cA + (qm) * 1024 +                   \
          (wr * 8 + mi * 2 + r3) * 64 + r7 * 8 + (((kk) * 4 + lhi) ^ r7)) * 8];          \
  } while (0)
#define DSB(dst, qn)                                                                     \
  do {                                                                                   \
    _Pragma("unroll") for (int ni = 0; ni < 2; ++ni)                                     \
    _Pragma("unroll") for (int kk = 0; kk < 2; ++kk)                                     \
      dst[ni * 2 + kk] = *(const s16x8*)&sm[(size_t)(cB + (qn) * 1024 +                  \
          (wc * 4 + ni * 2 + r3) * 64 + r7 * 8 + (((kk) * 4 + lhi) ^ r7)) * 8];          \
  } while (0)
#define STA(unit, k0, sbase)                                                             \
  do {                                                                                   \
    _Pragma("unroll") for (int l = 0; l < 2; ++l) {                                      \
      int c = l * 512 + tid;                                                             \
      int mid = (c >> 3) & 7;                                                            \
      int rowL = (c >> 6) * 8 + mid, khi = (c & 7) ^ mid;                                \
      int prow = (rowL >> 6) * 128 + (unit) * 64 + (rowL & 63);                          \
      gld_lds16(A + (size_t)(mt * 256 + prow) * Kdim + (k0) + khi * 8,                   \
                &sm[(size_t)((sbase) + (unit)*1024 + l * 512 + wave * 64) * 8]);         \
    }                                                                                    \
  } while (0)
#define STB(unit, k0, sbase)                                                             \
  do {                                                                                   \
    _Pragma("unroll") for (int l = 0; l < 2; ++l) {                                      \
      int c = l * 512 + tid;                                                             \
      int mid = (c >> 3) & 7;                                                            \
      int colL = (c >> 6) * 8 + mid, khi = (c & 7) ^ mid;                                \
      int pcol = (colL >> 5) * 64 + (unit) * 32 + (colL & 31);                           \
      gld_lds16(Bt + (size_t)(nt * 256 + pcol) * Kdim + (k0) + khi * 8,                  \
                &sm[(size_t)((sbase) + (unit)*1024 + l * 512 + wave * 64) * 8]);         \
    }                                                                                    \
  } while (0)
#define MM(qm, qn, BF)                                                                   \
  do {                                                                                   \
    __builtin_amdgcn_s_setprio(1);                                                       \
    _Pragma("unroll") for (int mi = 0; mi < 4; ++mi)                                     \
    _Pragma("unroll") for (int ni = 0; ni < 2; ++ni)                                     \
    _Pragma("unroll") for (int kk = 0; kk < 2; ++kk)                                     \
      acc[(qm) * 4 + mi][(qn) * 2 + ni] = __builtin_amdgcn_mfma_f32_16x16x32_bf16(       \
          af[mi * 2 + kk], BF[ni * 2 + kk], acc[(qm) * 4 + mi][(qn) * 2 + ni], 0, 0, 0); \
    __builtin_amdgcn_s_setprio(0);                                                       \
  } while (0)

  STA(0, 0, 0); STB(0, 0, 4096); STB(1, 0, 4096); STA(1, 0, 0);
  VMA(4);
  BARK;

  for (int t = 0; t < nK; ++t) {
    const int cA = (t & 1) * 2048, cB = 4096 + (t & 1) * 2048;
    const int sA = ((t & 1) ^ 1) * 2048, sB = 4096 + ((t & 1) ^ 1) * 2048;
    const int k1 = (t + 1) << 6;
    const bool st = (t + 1 < nK);
    s16x8 af[8], bf0[4], bf1[4];
    DSA(0); DSB(bf0, 0);
    if (st) { STA(0, k1, sA); VMA(4); } else { VMA(2); }
    BARK; MM(0, 0, bf0); BARK;
    DSB(bf1, 1);
    if (st) { STB(0, k1, sB); VMA(4); } else { VMA(0); }
    BARK; MM(0, 1, bf1); BARK;
    DSA(1);
    if (st) STB(1, k1, sB);
    BARK; MM(1, 1, bf1); BARK;
    if (st) { STA(1, k1, sA); VMA(4); }
    BARK; MM(1, 0, bf0); BARK;
  }
#undef VMA
#undef BARK
#undef DSA
#undef DSB
#undef STA
#undef STB
#undef MM

  const int row0 = mt * 256 + wr * 128;
  const int col0 = nt * 256 + wc * 64;
  float bcol[4];
#pragma unroll
  for (int ni = 0; ni < 4; ++ni) bcol[ni] = bias[col0 + ni * 16 + l15];
  if constexpr (EPI == 0) {
#pragma unroll
    for (int ni = 0; ni < 4; ++ni) {
      int cc = col0 + ni * 16 + l15;
      int which = cc >> 11, h = (cc >> 7) & 15, d = cc & 127;
      if (which == 2) {
#pragma unroll
        for (int mi = 0; mi < 8; ++mi) {
          int t0 = row0 + mi * 16 + lhi * 4;
          int bb = t0 >> 11, tt = t0 & 2047;
          u16x4 w;
#pragma unroll
          for (int j = 0; j < 4; ++j) w[j] = f2bf(acc[mi][ni][j] + bcol[ni]);
          *(u16x4*)&o2[(((size_t)bb * 16 + h) * 128 + d) * 2048 + tt] = w;
        }
      } else {
        u16* o = (which == 0) ? o0 : o1;
#pragma unroll
        for (int mi = 0; mi < 8; ++mi)
#pragma unroll
          for (int j = 0; j < 4; ++j) {
            int row = row0 + mi * 16 + lhi * 4 + j;
            int bb = row >> 11, tt = row & 2047;
            o[(((size_t)bb * 16 + h) * 2048 + tt) * 128 + d] = f2bf(acc[mi][ni][j] + bcol[ni]);
          }
      }
    }
  } else {
#pragma unroll
    for (int mi = 0; mi < 8; ++mi)
#pragma unroll
      for (int j = 0; j < 4; ++j) {
        int row = row0 + mi * 16 + lhi * 4 + j;
#pragma unroll
        for (int ni = 0; ni < 4; ++ni)
          ofp[(size_t)row * 2048 + col0 + ni * 16 + l15] = acc[mi][ni][j] + bcol[ni];
      }
  }
}

// ---------------- flash attention v5: R13 structure + XCD-local grid (bh on x) ----
__global__ __launch_bounds__(512, 4) void attn_k(
    const u16* __restrict__ Q, const u16* __restrict__ Kg,
    const u16* __restrict__ Vt, u16* __restrict__ Y) {
  __shared__ u16 Ks[8192];        // 16KB: chunk ci = dhi*64+key -> K[key][dhi*8..+7]
  __shared__ u16 Vs[8192];        // 16KB: chunk ci = khi*128+d  -> Vt[d][khi*8..+7]
  __shared__ u16 Ps[8][16 * 72];  // per-wave P tile, padded rows
  const int bh = blockIdx.x, p = blockIdx.y;   // bh fastest -> XCD-local K/V
  const int tid = threadIdx.x, lane = tid & 63, wave = tid >> 6;
  const int l15 = lane & 15, lhi = lane >> 4;
  const size_t bhT = (size_t)bh * 2048;
  const int b = bh >> 4, h = bh & 15;
  const float sc = 0.08838834764831845f * 1.4426950408889634f;  // 1/sqrt(128)*log2(e)

  for (int hf = 0; hf < 2; ++hf) {
    const int qt = hf ? 15 - p : p;          // 128-row q-tile index, 0..15
    const int r0 = qt * 128 + wave * 16;
    const int last = 2 * qt + 1;             // KV tiles 0..last (64 keys each)

    s16x8 qf[4];
#pragma unroll
    for (int kk = 0; kk < 4; ++kk)
      qf[kk] = *(const s16x8*)&Q[(bhT + r0 + l15) * 128 + kk * 32 + lhi * 8];

    f32x4 o[8] = {};
    float m_[4], l_[4];
#pragma unroll
    for (int j = 0; j < 4; ++j) { m_[j] = -1e30f; l_[j] = 0.f; }

    // prologue: stage KV tile 0 (WAR barrier vs previous half's reads)
    __syncthreads();
#pragma unroll
    for (int c = 0; c < 2; ++c) {
      int ci = c * 512 + tid;
      int dhi = ci >> 6, key = ci & 63;
      gld_lds16(Kg + (bhT + key) * 128 + dhi * 8, &Ks[(c * 512 + wave * 64) * 8]);
      int khi = ci >> 7, d = ci & 127;
      gld_lds16(Vt + ((size_t)bh * 128 + d) * 2048 + khi * 8, &Vs[(c * 512 + wave * 64) * 8]);
    }
    __syncthreads();

    for (int it = 0; it <= last; ++it) {
      const int j0 = it * 64;
      const bool have_next = (it < last);
      u16x8 kpre[2], vpre[2];
      if (have_next) {
        const int j1 = j0 + 64;
#pragma unroll
        for (int c = 0; c < 2; ++c) {
          int ci = c * 512 + tid;
          int dhi = ci >> 6, key = ci & 63;
          kpre[c] = *(const u16x8*)&Kg[(bhT + j1 + key) * 128 + dhi * 8];
          int khi = ci >> 7, d = ci & 127;
          vpre[c] = *(const u16x8*)&Vt[((size_t)bh * 128 + d) * 2048 + j1 + khi * 8];
        }
      }

      if (j0 <= r0 + 15) {  // wave has at least one unmasked (row,key) pair
        f32x4 s[4] = {};
        __builtin_amdgcn_s_setprio(1);
#pragma unroll
        for (int nc = 0; nc < 4; ++nc)
#pragma unroll
          for (int kk = 0; kk < 4; ++kk) {
            s16x8 kf = *(const s16x8*)&Ks[((kk * 4 + lhi) * 64 + nc * 16 + l15) * 8];
            s[nc] = __builtin_amdgcn_mfma_f32_16x16x32_bf16(qf[kk], kf, s[nc], 0, 0, 0);
          }
        __builtin_amdgcn_s_setprio(0);
        const bool maskt = (j0 + 63 > r0);
        float rmax[4];
#pragma unroll
        for (int j = 0; j < 4; ++j) rmax[j] = -1e30f;
#pragma unroll
        for (int nc = 0; nc < 4; ++nc)
#pragma unroll
          for (int j = 0; j < 4; ++j) {
            float v = s[nc][j] * sc;
            if (maskt && (j0 + nc * 16 + l15) > (r0 + lhi * 4 + j)) v = -1e30f;
            s[nc][j] = v;
            rmax[j] = fmaxf(rmax[j], v);
          }
#pragma unroll
        for (int off = 1; off < 16; off <<= 1)
#pragma unroll
          for (int j = 0; j < 4; ++j) rmax[j] = fmaxf(rmax[j], __shfl_xor(rmax[j], off));

        // T13 defer-max: only rescale when some row's max grew by > 8
        bool up = false;
#pragma unroll
        for (int j = 0; j < 4; ++j) up |= (rmax[j] > m_[j] + 8.f);
        if (__any(up)) {
#pragma unroll
          for (int j = 0; j < 4; ++j) {
            float mn = fmaxf(m_[j], rmax[j]);
            float al = exp2f(m_[j] - mn);
            m_[j] = mn;
            l_[j] *= al;
#pragma unroll
            for (int di = 0; di < 8; ++di) o[di][j] *= al;
          }
        }
        float rsum[4];
#pragma unroll
        for (int j = 0; j < 4; ++j) rsum[j] = 0.f;
#pragma unroll
        for (int nc = 0; nc < 4; ++nc)
#pragma unroll
          for (int j = 0; j < 4; ++j) {
            float pv = exp2f(s[nc][j] - m_[j]);   // bounded by 2^8 when deferred
            rsum[j] += pv;
            Ps[wave][(lhi * 4 + j) * 72 + nc * 16 + l15] = f2bf(pv);
          }
#pragma unroll
        for (int off = 1; off < 16; off <<= 1)
#pragma unroll
          for (int j = 0; j < 4; ++j) rsum[j] += __shfl_xor(rsum[j], off);
#pragma unroll
        for (int j = 0; j < 4; ++j) l_[j] += rsum[j];

        __builtin_amdgcn_s_setprio(1);
#pragma unroll
        for (int kk2 = 0; kk2 < 2; ++kk2) {
          s16x8 pf = *(const s16x8*)&Ps[wave][l15 * 72 + kk2 * 32 + lhi * 8];
#pragma unroll
          for (int di = 0; di < 8; ++di) {
            s16x8 vf = *(const s16x8*)&Vs[((kk2 * 4 + lhi) * 128 + di * 16 + l15) * 8];
            o[di] = __builtin_amdgcn_mfma_f32_16x16x32_bf16(pf, vf, o[di], 0, 0, 0);
          }
        }
        __builtin_amdgcn_s_setprio(0);
      }

      if (have_next) {
        __syncthreads();  // all waves done reading Ks/Vs
#pragma unroll
        for (int c = 0; c < 2; ++c) {
          *(u16x8*)&Ks[(c * 512 + tid) * 8] = kpre[c];
          *(u16x8*)&Vs[(c * 512 + tid) * 8] = vpre[c];
        }
        __syncthreads();  // staged for next iter
      }
    }

    float rl[4];
#pragma unroll
    for (int j = 0; j < 4; ++j) rl[j] = 1.0f / l_[j];
#pragma unroll
    for (int di = 0; di < 8; ++di)
#pragma unroll
      for (int j = 0; j < 4; ++j) {
        int row = b * 2048 + r0 + lhi * 4 + j;
        int col = h * 128 + di * 16 + l15;
        Y[(size_t)row * 2048 + col] = f2bf(o[di][j] * rl[j]);
      }
  }
}

extern "C" void kernel_launch(void* const* d_in, const int* in_sizes, int n_in,
                              void* d_out, int out_size, void* d_ws, size_t ws_size,
                              hipStream_t stream) {
  const float* x      = (const float*)d_in[0];
  const float* w_attn = (const float*)d_in[1];
  const float* b_attn = (const float*)d_in[2];
  const float* w_proj = (const float*)d_in[3];
  const float* b_proj = (const float*)d_in[4];
  float* out = (float*)d_out;

  char* ws = (char*)d_ws;
  u16* xb  = (u16*)(ws);                      // x bf16 [8192][2048]
  u16* waT = (u16*)(ws + 33554432ull);        // w_attn^T bf16 [6144][2048]
  u16* wpT = (u16*)(ws + 58720256ull);        // w_proj^T bf16 [2048][2048]
  u16* Qb  = (u16*)(ws + 67108864ull);        // [B,H,T,D]
  u16* Kb  = (u16*)(ws + 100663296ull);
  u16* Vtb = (u16*)(ws + 167772160ull);       // [B,H,D,T] (written by gemm1 epilogue)
  u16* Yb  = xb;                              // reuse (xb dead after gemm1)

  prep_k<<<12288, 256, 0, stream>>>(x, xb, w_attn, waT, w_proj, wpT);
  gemm256<0><<<32 * 24, 512, 0, stream>>>(xb, waT, b_attn, Qb, Kb, Vtb, nullptr, 24, 2048);
  attn_k<<<dim3(64, 8), 512, 0, stream>>>(Qb, Kb, Vtb, Yb);
  gemm256<1><<<32 * 8, 512, 0, stream>>>(Yb, wpT, b_proj, nullptr, nullptr, nullptr, out, 8, 2048);
}